// Round 7
// baseline (3892.736 us; speedup 1.0000x reference)
//
#include <hip/hip_runtime.h>
#include <math.h>

#define NA      128
#define NBATCH  2048
#define NTHR    256
#define NIT     300
#define NBIS    24      // ref does 40; bracket(~6)*2^-25 ~ 2e-7 = fp32 noise
#define SROW    132     // LDS row stride (floats): (132/4)%8==1 -> b128 conflict-free
#define LRC     0.02f
#define EPSC    1e-8f

// ---- wave64 cross-lane reductions via DPP (VALU pipe, no LDS traffic) ----
template <int CTRL>
__device__ __forceinline__ float dpp_sum_step(float x) {
  int s = __builtin_amdgcn_update_dpp(0, __float_as_int(x), CTRL, 0xF, 0xF, true);
  return x + __int_as_float(s);
}
__device__ __forceinline__ float wave_sum64(float x) {
  x = dpp_sum_step<0x111>(x);
  x = dpp_sum_step<0x112>(x);
  x = dpp_sum_step<0x114>(x);
  x = dpp_sum_step<0x118>(x);
  x = dpp_sum_step<0x142>(x);
  x = dpp_sum_step<0x143>(x);
  return x;  // total in lane 63
}
template <int CTRL>
__device__ __forceinline__ float dpp_mov_self(float x) {
  int s = __builtin_amdgcn_update_dpp(__float_as_int(x), __float_as_int(x), CTRL, 0xF, 0xF, false);
  return __int_as_float(s);
}
__device__ __forceinline__ float wave_min64(float x) {
  x = fminf(x, dpp_mov_self<0x111>(x));
  x = fminf(x, dpp_mov_self<0x112>(x));
  x = fminf(x, dpp_mov_self<0x114>(x));
  x = fminf(x, dpp_mov_self<0x118>(x));
  x = fminf(x, dpp_mov_self<0x142>(x));
  x = fminf(x, dpp_mov_self<0x143>(x));
  return x;
}
__device__ __forceinline__ float wave_max64(float x) {
  x = fmaxf(x, dpp_mov_self<0x111>(x));
  x = fmaxf(x, dpp_mov_self<0x112>(x));
  x = fmaxf(x, dpp_mov_self<0x114>(x));
  x = fmaxf(x, dpp_mov_self<0x118>(x));
  x = fmaxf(x, dpp_mov_self<0x142>(x));
  x = fmaxf(x, dpp_mov_self<0x143>(x));
  return x;
}
__device__ __forceinline__ float read_lane63(float x) {
  return __int_as_float(__builtin_amdgcn_readlane(__float_as_int(x), 63));
}
__device__ __forceinline__ float clip1(float x) {
  return __builtin_amdgcn_fmed3f(x, -1.0f, 1.0f);  // c = MAX_WEIGHT = 1
}

// One block per batch element, 256 threads. A lives in LDS (stride-132 rows,
// gamma folded at staging). R2-R6 forensic: the register allocator refuses to
// keep per-thread A tiles resident (VGPR_Count 100/56 for demand 128/64) and
// re-reads A from L2/L3 every iteration (~39 GB/dispatch) regardless of
// launch_bounds / waves_per_eu / asm pinning. LDS has deterministic cost:
// per-iter 64 per-lane b128 + 64 uniform b128 per block, conflict-free at
// stride 132 ((132/4)%8=1 -> rows hit distinct 4-bank groups).
// 69 KB LDS -> 2 blocks/CU (16 waves).
__global__ __launch_bounds__(NTHR)
void markowitz_kernel(
    const float* __restrict__ rets,
    const float* __restrict__ covmat,
    const float* __restrict__ gamma,
    const float* __restrict__ alpha,
    float* __restrict__ out)
{
  const int b    = blockIdx.x;
  const int tid  = threadIdx.x;
  const int r    = tid & (NA - 1);  // row 0..127
  const int h    = tid >> 7;        // half 0/1
  const int lane = tid & 63;
  const int wv   = tid >> 6;        // wave 0..3

  __shared__ __align__(16) float As[NA * SROW];  // 67,584 B
  __shared__ __align__(16) float ws[NA];
  __shared__ __align__(16) float vs[NA];
  __shared__ float partial[NTHR];
  __shared__ float pp[8];           // [0..3] wAw,ww per wave; [4,5] min; [6,7] max
  __shared__ float tau_s;

  // ---- stage A into LDS, gamma folded; global reads fully coalesced ----
  const float gm = gamma[b];
  const float4* G = reinterpret_cast<const float4*>(covmat + (size_t)b * NA * NA);
#pragma unroll
  for (int j = 0; j < 16; ++j) {
    const int idx = j * NTHR + tid;      // float4 index 0..4095
    float4 q = G[idx];
    const int row = idx >> 5;            // 32 float4 per row
    const int c4  = idx & 31;
    float4* dst = reinterpret_cast<float4*>(&As[row * SROW + c4 * 4]);
    *dst = make_float4(q.x * gm, q.y * gm, q.z * gm, q.w * gm);
  }
  const float r_t = rets[b * NA + r];    // used by h==0 threads
  const float av  = fabsf(alpha[b]);

  float w_t = 1.0f / NA;
  if (tid < NA) ws[tid] = w_t;
  __syncthreads();

  float v_t = 0.0f;
  const float4* Arow4 = reinterpret_cast<const float4*>(&As[r * SROW + h * 64]);
  const float4* ws4   = reinterpret_cast<const float4*>(ws) + 16 * h;

#pragma unroll 1
  for (int it = 0; it < NIT; ++it) {
    // ---- 1. half-row dot from LDS ----
    float4 acc = make_float4(0.f, 0.f, 0.f, 0.f);
#pragma unroll
    for (int k = 0; k < 16; ++k) {
      float4 ak = Arow4[k];   // per-lane b128, conflict-free (stride 132)
      float4 wk = ws4[k];     // wave-uniform b128 broadcast
      acc.x = fmaf(ak.x, wk.x, acc.x);
      acc.y = fmaf(ak.y, wk.y, acc.y);
      acc.z = fmaf(ak.z, wk.z, acc.z);
      acc.w = fmaf(ak.w, wk.w, acc.w);
    }
    partial[tid] = (acc.x + acc.y) + (acc.z + acc.w);
    __syncthreads();

    // ---- 2. combine halves; w.Aw and w.w reductions (threads 0..127) ----
    float Aw = 0.0f;
    if (tid < NA) {
      Aw = partial[tid] + partial[tid + NA];
      float p1 = wave_sum64(w_t * Aw);
      float p2 = wave_sum64(w_t * w_t);
      if (lane == 63) { pp[wv * 2 + 0] = p1; pp[wv * 2 + 1] = p2; }
    }
    __syncthreads();

    // ---- 3. gradient step + min/max bracket ----
    if (tid < NA) {
      const float risk = sqrtf(pp[0] + pp[2] + EPSC);
      const float nrm  = sqrtf(pp[1] + pp[3] + EPSC);
      const float g_t  = r_t - Aw / risk - av * (w_t / nrm);
      v_t = w_t + LRC * g_t;
      vs[tid] = v_t;
      float mn = wave_min64(v_t);
      float mx = wave_max64(v_t);
      if (lane == 63) { pp[4 + wv] = mn; pp[6 + wv] = mx; }
    }
    __syncthreads();

    // ---- 4. bisection for tau (wave 0; 2 elements per lane) ----
    if (wv == 0) {
      float v0 = vs[lane];
      float v1 = vs[lane + 64];
      float lo = fminf(pp[4], pp[5]) - 2.0f;  // min(v) - c - 1
      float hi = fmaxf(pp[6], pp[7]) + 1.0f;  // max(v) + c
#pragma unroll 1
      for (int rr = 0; rr < NBIS; ++rr) {
        const float mid = 0.5f * (lo + hi);
        float s = clip1(v0 - mid) + clip1(v1 - mid);
        s = wave_sum64(s);
        const float stot = read_lane63(s);
        const bool big = stot > 1.0f;
        lo = big ? mid : lo;
        hi = big ? hi : mid;
      }
      if (lane == 0) tau_s = 0.5f * (lo + hi);
    }
    __syncthreads();

    // ---- 5. project & publish new w ----
    if (tid < NA) {
      w_t = clip1(v_t - tau_s);
      ws[tid] = w_t;
    }
    __syncthreads();
  }

  if (tid < NA) out[b * NA + tid] = w_t;
}

extern "C" void kernel_launch(void* const* d_in, const int* in_sizes, int n_in,
                              void* d_out, int out_size, void* d_ws, size_t ws_size,
                              hipStream_t stream) {
  const float* rets   = (const float*)d_in[0];
  const float* covmat = (const float*)d_in[1];
  const float* gamma  = (const float*)d_in[2];
  const float* alpha  = (const float*)d_in[3];
  float* out = (float*)d_out;

  hipLaunchKernelGGL(markowitz_kernel, dim3(NBATCH), dim3(NTHR), 0, stream,
                     rets, covmat, gamma, alpha, out);
}

// Round 8
// 2685.382 us; speedup vs baseline: 1.4496x; 1.4496x over previous
//
#include <hip/hip_runtime.h>
#include <math.h>

#define NA      128
#define NBATCH  2048
#define NTHR    512
#define NIT     300
#define NBIS    40      // full 40: R7 showed NBIS=24 -> absmax 8e-3 (4e4x amplification of tau noise)
#define LRC     0.02f
#define EPSC    1e-8f

// ---- wave64 cross-lane reductions via DPP (VALU pipe, no LDS traffic) ----
template <int CTRL>
__device__ __forceinline__ float dpp_sum_step(float x) {
  int s = __builtin_amdgcn_update_dpp(0, __float_as_int(x), CTRL, 0xF, 0xF, true);
  return x + __int_as_float(s);
}
__device__ __forceinline__ float wave_sum64(float x) {
  x = dpp_sum_step<0x111>(x);
  x = dpp_sum_step<0x112>(x);
  x = dpp_sum_step<0x114>(x);
  x = dpp_sum_step<0x118>(x);
  x = dpp_sum_step<0x142>(x);
  x = dpp_sum_step<0x143>(x);
  return x;  // total in lane 63
}
template <int CTRL>
__device__ __forceinline__ float dpp_mov_self(float x) {
  int s = __builtin_amdgcn_update_dpp(__float_as_int(x), __float_as_int(x), CTRL, 0xF, 0xF, false);
  return __int_as_float(s);
}
__device__ __forceinline__ float wave_min64(float x) {
  x = fminf(x, dpp_mov_self<0x111>(x));
  x = fminf(x, dpp_mov_self<0x112>(x));
  x = fminf(x, dpp_mov_self<0x114>(x));
  x = fminf(x, dpp_mov_self<0x118>(x));
  x = fminf(x, dpp_mov_self<0x142>(x));
  x = fminf(x, dpp_mov_self<0x143>(x));
  return x;  // min in lane 63
}
__device__ __forceinline__ float wave_max64(float x) {
  x = fmaxf(x, dpp_mov_self<0x111>(x));
  x = fmaxf(x, dpp_mov_self<0x112>(x));
  x = fmaxf(x, dpp_mov_self<0x114>(x));
  x = fmaxf(x, dpp_mov_self<0x118>(x));
  x = fmaxf(x, dpp_mov_self<0x142>(x));
  x = fmaxf(x, dpp_mov_self<0x143>(x));
  return x;  // max in lane 63
}
__device__ __forceinline__ float bcast63(float x) {
  return __int_as_float(__builtin_amdgcn_readlane(__float_as_int(x), 63));
}
__device__ __forceinline__ float clip1(float x) {
  return __builtin_amdgcn_fmed3f(x, -1.0f, 1.0f);  // c = MAX_WEIGHT = 1
}

// One block per batch element, 512 threads (8 waves). Thread (r = tid&127,
// q = tid>>7) owns QUARTER-row r, columns 32q..32q+31 -> 8 float4 = 32 VGPRs.
//
// R2-R7 forensic: the register allocator targets ~8 waves/EU (~64 regs) and
// spills/remats ANY A-tile exceeding that (demand 128 -> picked 100; demand
// 64 -> picked 56), producing ~39 GB/dispatch of L2/L3 re-reads. LDS-A (R7)
// fixed traffic but died on concurrency (2 blocks/CU, waves idle during the
// serial bisection). This version makes per-thread demand (~55) FIT the
// allocator's preferred budget: A register-resident, LDS ~4 KB ->
// 4 blocks/CU, 32 waves/CU. Bisection runs on wave (b&7) per block so chains
// from co-resident blocks land on different SIMDs; the block's other waves
// sleep at the barrier (no issue burned) while other blocks' work fills in.
__global__ __launch_bounds__(NTHR)
void markowitz_kernel(
    const float* __restrict__ rets,
    const float* __restrict__ covmat,
    const float* __restrict__ gamma,
    const float* __restrict__ alpha,
    float* __restrict__ out)
{
  const int b    = blockIdx.x;
  const int tid  = threadIdx.x;
  const int r    = tid & (NA - 1);  // row 0..127
  const int q    = tid >> 7;        // quarter 0..3 (uniform within a wave)
  const int lane = tid & 63;
  const int wv   = tid >> 6;        // wave 0..7
  const int chain_wv = b & 7;       // which wave runs the bisection chain

  __shared__ __align__(16) float ws[NA];     // current weights
  __shared__ __align__(16) float vs[NA];     // pre-projection vector
  __shared__ __align__(16) float part[NTHR]; // quarter-row dot partials (part[tid])
  __shared__ float pp[4];                    // wAw, ww per wave 0/1

  // ---- one-time: stage quarter-row of A into registers, gamma folded ----
  const float gm = gamma[b];
  const float4* Aq = reinterpret_cast<const float4*>(
      covmat + (size_t)b * NA * NA + (size_t)r * NA + (size_t)q * 32);
  float4 a[8];
#pragma unroll
  for (int k = 0; k < 8; ++k) {
    float4 t = Aq[k];
    a[k] = make_float4(t.x * gm, t.y * gm, t.z * gm, t.w * gm);
  }
  const float av = fabsf(alpha[b]);
  float r_c = 0.0f;
  if (tid < NA) { r_c = rets[b * NA + tid]; ws[tid] = 1.0f / NA; }
  __syncthreads();

#pragma unroll 1
  for (int it = 0; it < NIT; ++it) {
    // ---- 1. quarter-row dot (A in regs; w via wave-uniform LDS broadcast) ----
    const float4* w4 = reinterpret_cast<const float4*>(ws) + q * 8;
    float4 acc = make_float4(0.f, 0.f, 0.f, 0.f);
#pragma unroll
    for (int k = 0; k < 8; ++k) {
      float4 wk = w4[k];  // uniform address within wave -> broadcast b128
      acc.x = fmaf(a[k].x, wk.x, acc.x);
      acc.y = fmaf(a[k].y, wk.y, acc.y);
      acc.z = fmaf(a[k].z, wk.z, acc.z);
      acc.w = fmaf(a[k].w, wk.w, acc.w);
    }
    part[tid] = (acc.x + acc.y) + (acc.z + acc.w);
    __syncthreads();

    // ---- 2. combine quarters; wAw / ww reductions (waves 0,1) ----
    float Aw = 0.f, w_c = 0.f, v_c = 0.f;
    if (tid < NA) {
      Aw  = (part[tid] + part[tid + NA]) + (part[tid + 2 * NA] + part[tid + 3 * NA]);
      w_c = ws[tid];
      float p1 = wave_sum64(w_c * Aw);
      float p2 = wave_sum64(w_c * w_c);
      if (lane == 63) { pp[wv * 2 + 0] = p1; pp[wv * 2 + 1] = p2; }
    }
    __syncthreads();

    // ---- 3. gradient step -> v (waves 0,1) ----
    if (tid < NA) {
      const float risk = sqrtf(pp[0] + pp[2] + EPSC);
      const float nrm  = sqrtf(pp[1] + pp[3] + EPSC);
      const float g    = r_c - Aw / risk - av * (w_c / nrm);
      v_c = w_c + LRC * g;
      vs[tid] = v_c;
    }
    __syncthreads();

    // ---- 4. bisection + projection on the chain wave only ----
    if (wv == chain_wv) {
      float v0 = vs[lane];
      float v1 = vs[lane + 64];
      float mn = bcast63(wave_min64(fminf(v0, v1)));
      float mx = bcast63(wave_max64(fmaxf(v0, v1)));
      float lo = mn - 2.0f;   // min(v) - c - 1
      float hi = mx + 1.0f;   // max(v) + c
#pragma unroll 1
      for (int rr = 0; rr < NBIS; ++rr) {
        const float mid = 0.5f * (lo + hi);
        float s = wave_sum64(clip1(v0 - mid) + clip1(v1 - mid));
        const float st = bcast63(s);
        const bool big = st > 1.0f;
        lo = big ? mid : lo;
        hi = big ? hi : mid;
      }
      const float tau = 0.5f * (lo + hi);
      ws[lane]      = clip1(v0 - tau);
      ws[lane + 64] = clip1(v1 - tau);
    }
    __syncthreads();
  }

  if (tid < NA) out[b * NA + tid] = ws[tid];
}

extern "C" void kernel_launch(void* const* d_in, const int* in_sizes, int n_in,
                              void* d_out, int out_size, void* d_ws, size_t ws_size,
                              hipStream_t stream) {
  const float* rets   = (const float*)d_in[0];
  const float* covmat = (const float*)d_in[1];
  const float* gamma  = (const float*)d_in[2];
  const float* alpha  = (const float*)d_in[3];
  float* out = (float*)d_out;

  hipLaunchKernelGGL(markowitz_kernel, dim3(NBATCH), dim3(NTHR), 0, stream,
                     rets, covmat, gamma, alpha, out);
}